// Round 11
// baseline (161.513 us; speedup 1.0000x reference)
//
#include <hip/hip_runtime.h>
#include <hip/hip_bf16.h>
#include <cstdint>

// SelfSimilarity: out[b,i,j] = softmax_j( -T * max(||x_i - x_j||^2, 0) )
// bf16 MFMA via norm expansion; ||x||^2 from ROUNDED bf16 values so the
// diagonal logit is exactly 0 => max logit 0 => no online max needed.
//
// V10: occupancy attack on the sweep. Ledger: store-side theories all null
// (V8 NT, V9 fill-geometry); sweep ~60us is latency-bound (MfmaUtil 3.5%,
// VALUBusy 11%, Occ 31%, 2 waves/SIMD, P=128 f32/lane -> VGPR ~170).
// Change: 512-thread blocks, 8 waves; wave w (group g=w>>2) owns cols
// (w&3)*32 of j-tiles [8g, 8g+8) -> P halves to 64 f32/lane, VGPR
// target <=128 (launch_bounds(512,4)) -> 2 blocks/CU = 4 waves/SIMD (2x
// hiding), and each wave's dependent chain halves (8 tiles not 16).
// Keeps: single sweep, swapped MFMA, direct-L2 B loads, XCD batch pinning,
// LDS-transposed epilogue (verified swizzle, 0 conflicts), plain stores.

using bf16x8 = __attribute__((ext_vector_type(8))) short;
using f32x4  = __attribute__((ext_vector_type(4))) float;

#define TEMP   (1.0f / 13.544f)
#define LOG2E  1.4426950408889634f

// ---------------------------------------------------------------------------
// prep: fp32 -> bf16 (RNE) in MFMA-staging layout + csq[row] = -T*log2e*||x_bf||^2
// ws bf16 layout: [b][group=row>>4][qblock=k>>3][r=row&15][8 elems]
//   -> uint4 index: (b*128+g)*256 + q*16 + r
// ---------------------------------------------------------------------------
__global__ __launch_bounds__(256) void prep_kernel(
    const float* __restrict__ x, uint4* __restrict__ xbf, float* __restrict__ csq)
{
    const int t   = threadIdx.x;
    const int lr  = t >> 4;            // local row 0..15
    const int q   = t & 15;            // k-block of 8
    const int row = blockIdx.x * 16 + lr;   // 0..16383

    const float* xp = x + (size_t)row * 128 + q * 8;
    float4 a0 = *(const float4*)(xp);
    float4 a1 = *(const float4*)(xp + 4);
    float v[8] = {a0.x, a0.y, a0.z, a0.w, a1.x, a1.y, a1.z, a1.w};

    unsigned u[8];
    float s = 0.f;
#pragma unroll
    for (int e = 0; e < 8; ++e) {
        unsigned ui = __float_as_uint(v[e]);
        unsigned r  = (ui + 0x7FFFu + ((ui >> 16) & 1u)) >> 16;   // RNE to bf16
        u[e] = r;
        float d = __uint_as_float(r << 16);                        // decoded value
        s += d * d;                                                // norm of ROUNDED vec
    }
    uint4 pack;
    pack.x = u[0] | (u[1] << 16);
    pack.y = u[2] | (u[3] << 16);
    pack.z = u[4] | (u[5] << 16);
    pack.w = u[6] | (u[7] << 16);

    const int b  = row >> 11;
    const int g  = (row >> 4) & 127;
    const int rr = row & 15;
    xbf[(b * 128 + g) * 256 + q * 16 + rr] = pack;

#pragma unroll
    for (int m = 1; m < 16; m <<= 1) s += __shfl_xor(s, m, 64);
    if (q == 0) csq[row] = s * (-TEMP * LOG2E);
}

// ---------------------------------------------------------------------------
// main: per workgroup, M=16 rows x all 2048 cols, ONE sweep, 8 waves.
// Wave w: group g=w>>2 -> j-tiles [8g, 8g+8); cols cw=(w&3)*32 within tile.
// Swapped MFMA: lane holds output row i0+l15, 4 consecutive j per fragment.
// P[8][2] f32x4 = 64 f32/lane. After the 8-wave inv reduction, a 4-round
// LDS-transposed epilogue (4 tiles/round: 2 per group) emits contiguous
// full-line stores.
// logit2 = log2e*(-T*dist) = C2L*dot + csq_i + csq_j, clamped <= 0.
// ---------------------------------------------------------------------------
__global__ __launch_bounds__(512, 4) void sim_kernel(
    const uint4* __restrict__ xbf, const float* __restrict__ csq, float* __restrict__ out)
{
    const int blk  = blockIdx.x;
    const int b    = blk & 7;             // batch pinned to XCD (round-robin dispatch)
    const int i0   = (blk >> 3) * 16;     // 128 row-tiles per batch
    const int tid  = threadIdx.x;
    const int w    = tid >> 6;            // wave 0..7
    const int g    = w >> 2;              // tile-group 0..1
    const int lane = tid & 63;
    const int quad = lane >> 4;
    const int l15  = lane & 15;

    __shared__ __align__(16) char lsP[4][8192];   // epilogue: 4 x (16x128 f32 tile)
    __shared__ float lsSum[8][16];
    __shared__ __align__(16) float lsInv[16];

    const uint4* xbb  = xbf + (size_t)b * (128 * 256);
    const float* csqb = csq + b * 2048;

    // A fragments (i-rows): lane holds row i0+l15, k-chunk k4*4+quad.
    bf16x8 afrag[4];
#pragma unroll
    for (int k4 = 0; k4 < 4; ++k4) {
        uint4 vv = xbb[(i0 >> 4) * 256 + (k4 * 4 + quad) * 16 + l15];
        afrag[k4] = __builtin_bit_cast(bf16x8, vv);
    }

    const float csqi = csqb[i0 + l15];    // i is lane-local after the swap
    const float C2L  = 2.0f * TEMP * LOG2E;
    const int   cw   = (w & 3) * 32;

    // ---- single sweep: 8 tiles per wave, P into registers, sums inline ----
    f32x4 P0[8], P1[8];
    float sum_ = 0.f;
#pragma unroll
    for (int lt = 0; lt < 8; ++lt) {
        const int jt = g * 8 + lt;
        const int j0 = jt * 128;
        float4 cj0 = *(const float4*)(csqb + j0 + cw + quad * 4);
        float4 cj1 = *(const float4*)(csqb + j0 + cw + 16 + quad * 4);

        // B fragments direct from L2: 64 lanes x 16B contiguous per wave-op.
        const uint4* b0p = xbb + (size_t)(jt * 8 + (w & 3) * 2) * 256 + quad * 16 + l15;
        const uint4* b1p = b0p + 256;

        f32x4 acc[2] = {};
#pragma unroll
        for (int k4 = 0; k4 < 4; ++k4) {
            bf16x8 b0 = __builtin_bit_cast(bf16x8, b0p[k4 * 64]);
            bf16x8 b1 = __builtin_bit_cast(bf16x8, b1p[k4 * 64]);
            // swapped operands: lane = i-row, regs = 4 consecutive j
            acc[0] = __builtin_amdgcn_mfma_f32_16x16x32_bf16(b0, afrag[k4], acc[0], 0, 0, 0);
            acc[1] = __builtin_amdgcn_mfma_f32_16x16x32_bf16(b1, afrag[k4], acc[1], 0, 0, 0);
        }

        f32x4 p0, p1;
        p0[0] = exp2f(fminf(fmaf(C2L, acc[0][0], csqi + cj0.x), 0.f));
        p0[1] = exp2f(fminf(fmaf(C2L, acc[0][1], csqi + cj0.y), 0.f));
        p0[2] = exp2f(fminf(fmaf(C2L, acc[0][2], csqi + cj0.z), 0.f));
        p0[3] = exp2f(fminf(fmaf(C2L, acc[0][3], csqi + cj0.w), 0.f));
        p1[0] = exp2f(fminf(fmaf(C2L, acc[1][0], csqi + cj1.x), 0.f));
        p1[1] = exp2f(fminf(fmaf(C2L, acc[1][1], csqi + cj1.y), 0.f));
        p1[2] = exp2f(fminf(fmaf(C2L, acc[1][2], csqi + cj1.z), 0.f));
        p1[3] = exp2f(fminf(fmaf(C2L, acc[1][3], csqi + cj1.w), 0.f));
        P0[lt] = p0;
        P1[lt] = p1;
        sum_ += p0[0] + p0[1] + p0[2] + p0[3] + p1[0] + p1[1] + p1[2] + p1[3];
    }

    // ---- reduce: across quads (lane bits 4,5), then across 8 waves --------
    sum_ += __shfl_xor(sum_, 16, 64);
    sum_ += __shfl_xor(sum_, 32, 64);
    if (quad == 0) lsSum[w][l15] = sum_;
    __syncthreads();
    if (tid < 16) {
        float tot = 0.f;
#pragma unroll
        for (int k = 0; k < 8; ++k) tot += lsSum[k][tid];
        lsInv[tid] = 1.0f / tot;
    }
    __syncthreads();
    const float inv = lsInv[l15];

    // ---- epilogue: 4 rounds x (stage 4 tiles, contiguous store) -----------
    // Round rd stages tiles {2rd, 2rd+1} (group 0 -> lsP[0],lsP[1]) and
    // {8+2rd, 9+2rd} (group 1 -> lsP[2],lsP[3]). LDS write: row l15
    // (512B stride), 16B slots XOR-swizzled by row&7 (verified: correct,
    // 0 bank conflicts). Store: 512 threads cover 4 tiles; thread ->
    // tile tb=tid>>7, row r=(tid>>3)&15, chunk c=tid&7; 4 passes of 16B.
    const int wr   = l15 << 9;                // l15 * 512
    const int ws   = (l15 & 7) << 4;
    const int wc0  = (cw << 2) + (quad << 4); // byte col of p0
    const int tb   = tid >> 7;                // 0..3
    const int rr   = (tid >> 3) & 15;         // row 0..15
    const int cc   = (tid & 7) << 4;          // byte chunk 0..112
    const int rsw  = (rr & 7) << 4;
    char* obase = (char*)(out + ((size_t)b * 2048 + i0) * 2048);

#pragma unroll
    for (int rd = 0; rd < 4; ++rd) {
#pragma unroll
        for (int q = 0; q < 2; ++q) {
            const int lt = rd * 2 + q;
            char* buf = lsP[g * 2 + q];
            f32x4 s0 = P0[lt] * inv;
            f32x4 s1 = P1[lt] * inv;
            *(f32x4*)(buf + wr + ((wc0)      ^ ws)) = s0;
            *(f32x4*)(buf + wr + ((wc0 + 64) ^ ws)) = s1;
        }
        __syncthreads();
        {
            const int jt = rd * 2 + (tb & 1) + 8 * (tb >> 1);
            const char* buf = lsP[tb];
            char* orow = obase + (size_t)rr * 8192 + jt * 512;
#pragma unroll
            for (int pass = 0; pass < 4; ++pass) {
                const int bc = cc + pass * 128;
                f32x4 v = *(const f32x4*)(buf + (rr << 9) + (bc ^ rsw));
                *(f32x4*)(orow + bc) = v;
            }
        }
        __syncthreads();   // before next round overwrites lsP
    }
}

extern "C" void kernel_launch(void* const* d_in, const int* in_sizes, int n_in,
                              void* d_out, int out_size, void* d_ws, size_t ws_size,
                              hipStream_t stream) {
    const float* x   = (const float*)d_in[0];
    float*       out = (float*)d_out;
    // ws: [0, 4MB) packed bf16 x; [4MB, 4MB+64KB) csq. Needs ~4.26 MB of ws.
    uint4* xbf = (uint4*)d_ws;
    float* csq = (float*)((char*)d_ws + (size_t)4 * 1024 * 1024);

    prep_kernel<<<1024, 256, 0, stream>>>(x, xbf, csq);     // 16384 rows
    sim_kernel<<<1024, 512, 0, stream>>>(xbf, csq, out);    // 8 batches x 128 row-tiles
}